// Round 1
// baseline (930.435 us; speedup 1.0000x reference)
//
#include <hip/hip_runtime.h>

#define EPSV 1e-5f

// ---------------- CSR build ----------------
__global__ __launch_bounds__(256) void k_hist(const int* __restrict__ dst, int E, int* __restrict__ cnt){
  for (int e = blockIdx.x*256+threadIdx.x; e < E; e += gridDim.x*256)
    atomicAdd(&cnt[dst[e]], 1);
}

__global__ __launch_bounds__(256) void k_dis(const int* __restrict__ cnt, float* __restrict__ dis, int n){
  for (int i = blockIdx.x*256+threadIdx.x; i < n; i += gridDim.x*256)
    dis[i] = rsqrtf((float)(cnt[i]+1));
}

// exclusive scan, 2048 elems/block
__global__ __launch_bounds__(256) void k_scan1(const int* __restrict__ cnt, int* __restrict__ rp,
                                               int* __restrict__ bsums, int n){
  __shared__ int sh[2][256];
  int tid = threadIdx.x;
  int base = blockIdx.x*2048 + tid*8;
  int v[8]; int s = 0;
  #pragma unroll
  for (int j=0;j<8;++j){ v[j] = (base+j<n)? cnt[base+j]:0; s += v[j]; }
  int pa = 0; sh[0][tid] = s; __syncthreads();
  for (int off=1; off<256; off<<=1){
    int add = (tid>=off)? sh[pa][tid-off] : 0;
    sh[pa^1][tid] = sh[pa][tid] + add;
    pa ^= 1; __syncthreads();
  }
  int incl = sh[pa][tid];
  if (tid==255) bsums[blockIdx.x] = incl;
  int run = incl - s;
  #pragma unroll
  for (int j=0;j<8;++j){ if (base+j<n) rp[base+j] = run; run += v[j]; }
}

__global__ void k_scan2(int* __restrict__ bsums, int nb){
  if (threadIdx.x==0 && blockIdx.x==0){
    int r=0;
    for (int i=0;i<nb;++i){ int t=bsums[i]; bsums[i]=r; r+=t; }
  }
}

__global__ __launch_bounds__(256) void k_scan3(int* __restrict__ rp, int* __restrict__ cur,
                                               const int* __restrict__ bsums, int n, int E){
  for (int i = blockIdx.x*256+threadIdx.x; i<n; i+=gridDim.x*256){
    int v = rp[i] + bsums[i>>11];
    rp[i] = v; cur[i] = v;
  }
  if (blockIdx.x==0 && threadIdx.x==0) rp[n] = E;
}

__global__ __launch_bounds__(256) void k_fill(const int* __restrict__ src, const int* __restrict__ dst,
                                              int E, int* __restrict__ cur, int* __restrict__ col){
  for (int e = blockIdx.x*256+threadIdx.x; e<E; e+=gridDim.x*256){
    int d = dst[e];
    int pos = atomicAdd(&cur[d], 1);
    col[pos] = src[e];
  }
}

// ---------------- graph segment offsets (batch is sorted) ----------------
__global__ __launch_bounds__(256) void k_gsinit(int* __restrict__ gs, int G, int n){
  for (int t = blockIdx.x*256+threadIdx.x; t<=G; t+=gridDim.x*256) gs[t] = n;
}
__global__ __launch_bounds__(256) void k_gsbound(const int* __restrict__ batch, int n, int* __restrict__ gs){
  for (int i = blockIdx.x*256+threadIdx.x; i<n; i+=gridDim.x*256){
    int b = batch[i];
    int prev = (i==0)? -1 : batch[i-1];
    for (int g = prev+1; g<=b; ++g) gs[g] = i;
  }
}

// ---------------- GEMM: out[i][:] = dis[i] * (bnrelu?(X[i,:]) @ W) ----------------
// wave: 16 col-quads x 4 row-groups, 8 rows per group => 32 rows/wave
template<int K, bool BN>
__global__ __launch_bounds__(256) void k_gemm(const float* __restrict__ X, const float* __restrict__ W,
    const float* __restrict__ dis, const float* __restrict__ ac,
    float* __restrict__ out, int n, int nchunks)
{
  __shared__ float4 Wl[K*16];
  __shared__ float2 acS[64];
  for (int t = threadIdx.x; t < K*16; t += 256)
    Wl[t] = reinterpret_cast<const float4*>(W)[t];
  if (BN){ if (threadIdx.x < 64) acS[threadIdx.x] = make_float2(ac[threadIdx.x], ac[64+threadIdx.x]); }
  __syncthreads();
  int wave = threadIdx.x>>6, lane = threadIdx.x&63;
  int cg = lane&15, rg = lane>>4;
  for (int chunk = blockIdx.x*4+wave; chunk < nchunks; chunk += gridDim.x*4){
    int rowbase = chunk*32 + rg*8;
    float4 acc[8];
    #pragma unroll
    for (int r=0;r<8;++r) acc[r] = make_float4(0.f,0.f,0.f,0.f);
    for (int k=0;k<K;k+=4){
      float4 w0 = Wl[(k+0)*16+cg];
      float4 w1 = Wl[(k+1)*16+cg];
      float4 w2 = Wl[(k+2)*16+cg];
      float4 w3 = Wl[(k+3)*16+cg];
      float2 p0,p1,p2,p3;
      if (BN){ p0=acS[k]; p1=acS[k+1]; p2=acS[k+2]; p3=acS[k+3]; }
      #pragma unroll
      for (int r=0;r<8;++r){
        int row = rowbase+r;
        float4 xq = make_float4(0.f,0.f,0.f,0.f);
        if (row < n) xq = *reinterpret_cast<const float4*>(X + (size_t)row*K + k);
        if (BN){
          xq.x = fmaxf(fmaf(xq.x,p0.x,p0.y), 0.f);
          xq.y = fmaxf(fmaf(xq.y,p1.x,p1.y), 0.f);
          xq.z = fmaxf(fmaf(xq.z,p2.x,p2.y), 0.f);
          xq.w = fmaxf(fmaf(xq.w,p3.x,p3.y), 0.f);
        }
        acc[r].x = fmaf(xq.w,w3.x, fmaf(xq.z,w2.x, fmaf(xq.y,w1.x, fmaf(xq.x,w0.x, acc[r].x))));
        acc[r].y = fmaf(xq.w,w3.y, fmaf(xq.z,w2.y, fmaf(xq.y,w1.y, fmaf(xq.x,w0.y, acc[r].y))));
        acc[r].z = fmaf(xq.w,w3.z, fmaf(xq.z,w2.z, fmaf(xq.y,w1.z, fmaf(xq.x,w0.z, acc[r].z))));
        acc[r].w = fmaf(xq.w,w3.w, fmaf(xq.z,w2.w, fmaf(xq.y,w1.w, fmaf(xq.x,w0.w, acc[r].w))));
      }
    }
    #pragma unroll
    for (int r=0;r<8;++r){
      int row = rowbase+r;
      if (row < n){
        float d = dis[row];
        float4 o = make_float4(acc[r].x*d, acc[r].y*d, acc[r].z*d, acc[r].w*d);
        *reinterpret_cast<float4*>(out + (size_t)row*64 + cg*4) = o;
      }
    }
  }
}

// ---------------- aggregation + bias + BN-stat partials ----------------
__global__ __launch_bounds__(256) void k_agg(const float* __restrict__ H, const int* __restrict__ rp,
    const int* __restrict__ col, const float* __restrict__ dis, const float* __restrict__ bias,
    float* __restrict__ out, float* __restrict__ stats, int n)
{
  int wave = threadIdx.x>>6, lane = threadIdx.x&63;
  float bj = bias[lane];
  float bsum = 0.f, bsq = 0.f;
  int nw = gridDim.x*4;
  for (int i = blockIdx.x*4+wave; i<n; i+=nw){
    int s = rp[i], e = rp[i+1];
    float acc = H[(size_t)i*64+lane];
    int t = s;
    for (; t+4 <= e; t += 4){
      int c0 = col[t], c1 = col[t+1], c2 = col[t+2], c3 = col[t+3];
      float v0 = H[(size_t)c0*64+lane];
      float v1 = H[(size_t)c1*64+lane];
      float v2 = H[(size_t)c2*64+lane];
      float v3 = H[(size_t)c3*64+lane];
      acc += (v0+v1)+(v2+v3);
    }
    for (; t<e; ++t) acc += H[(size_t)col[t]*64+lane];
    float v = fmaf(dis[i], acc, bj);
    out[(size_t)i*64+lane] = v;
    bsum += v; bsq = fmaf(v, v, bsq);
  }
  __shared__ float red[2][4][64];
  red[0][wave][lane] = bsum; red[1][wave][lane] = bsq;
  __syncthreads();
  if (wave==0){
    float s0 = (red[0][0][lane]+red[0][1][lane]) + (red[0][2][lane]+red[0][3][lane]);
    float q0 = (red[1][0][lane]+red[1][1][lane]) + (red[1][2][lane]+red[1][3][lane]);
    atomicAdd(&stats[lane], s0);
    atomicAdd(&stats[64+lane], q0);
  }
}

// ---------------- BN finalize: a = g*rstd, c = bt - mu*a ----------------
__global__ void k_final(const float* __restrict__ stats, const float* __restrict__ g,
                        const float* __restrict__ bt, float* __restrict__ ac, int n){
  int j = threadIdx.x;
  if (j < 64){
    float fn = (float)n;
    float mu = stats[j]/fn;
    float var = stats[64+j]/fn - mu*mu;
    float rstd = rsqrtf(var + EPSV);
    float a = rstd*g[j];
    ac[j] = a;
    ac[64+j] = bt[j] - mu*a;
  }
}

// ---------------- mean-pool with fused BN+ReLU ----------------
__global__ __launch_bounds__(256) void k_pool(const float* __restrict__ agg, const float* __restrict__ ac,
                                              const int* __restrict__ gs, float* __restrict__ pooled){
  int g = blockIdx.x;
  int s = gs[g], e = gs[g+1];
  int wave = threadIdx.x>>6, lane = threadIdx.x&63;
  float a = ac[lane], c = ac[64+lane];
  float acc = 0.f;
  for (int i = s+wave; i < e; i += 4)
    acc += fmaxf(fmaf(agg[(size_t)i*64+lane], a, c), 0.f);
  __shared__ float red[4][64];
  red[wave][lane] = acc; __syncthreads();
  if (wave==0){
    float t = (red[0][lane]+red[1][lane]) + (red[2][lane]+red[3][lane]);
    float cg = (float)(e - s);
    pooled[(size_t)g*64+lane] = t / fmaxf(cg, 1.f);
  }
}

// ---------------- FC + log_softmax ----------------
__global__ __launch_bounds__(256) void k_logits(const float* __restrict__ pooled, const float* __restrict__ fcW,
                                                const float* __restrict__ fcb, float* __restrict__ out, int G){
  int gw = (blockIdx.x*256 + threadIdx.x) >> 6;
  int lane = threadIdx.x & 63;
  if (gw >= G) return;
  float l = -1e30f;
  if (lane < 10){
    l = fcb[lane];
    for (int k=0;k<64;++k) l = fmaf(pooled[(size_t)gw*64+k], fcW[k*10+lane], l);
  }
  float m = l;
  for (int off=32; off; off>>=1) m = fmaxf(m, __shfl_xor(m, off));
  float ex = (lane<10)? expf(l-m) : 0.f;
  float ssum = ex;
  for (int off=32; off; off>>=1) ssum += __shfl_xor(ssum, off);
  if (lane < 10) out[(size_t)gw*10+lane] = l - m - logf(ssum);
}

extern "C" void kernel_launch(void* const* d_in, const int* in_sizes, int n_in,
                              void* d_out, int out_size, void* d_ws, size_t ws_size,
                              hipStream_t stream){
  const float* x    = (const float*)d_in[0];
  const int*   ei   = (const int*)d_in[1];
  const int*   batch= (const int*)d_in[2];
  const float* W1 = (const float*)d_in[3];  const float* b1 = (const float*)d_in[4];
  const float* g1 = (const float*)d_in[5];  const float* bt1= (const float*)d_in[6];
  const float* W2 = (const float*)d_in[7];  const float* b2 = (const float*)d_in[8];
  const float* g2 = (const float*)d_in[9];  const float* bt2= (const float*)d_in[10];
  const float* W3 = (const float*)d_in[11]; const float* b3 = (const float*)d_in[12];
  const float* g3 = (const float*)d_in[13]; const float* bt3= (const float*)d_in[14];
  const float* W4 = (const float*)d_in[15]; const float* b4 = (const float*)d_in[16];
  const float* g4 = (const float*)d_in[17]; const float* bt4= (const float*)d_in[18];
  const float* fcW= (const float*)d_in[19]; const float* fcb= (const float*)d_in[20];

  int n = in_sizes[0] / 128;
  int E = in_sizes[1] / 2;
  int G = out_size / 10;
  const int* src = ei;
  const int* dst = ei + E;

  // workspace carve (256B aligned)
  char* p = (char*)d_ws;
  auto alloc = [&](size_t bytes)->void*{ void* r = p; p += (bytes + 255) & ~(size_t)255; return r; };
  int*   cnt    = (int*)  alloc((size_t)n*4);
  int*   rowptr = (int*)  alloc((size_t)(n+1)*4);
  int*   cursor = (int*)  alloc((size_t)(n+1)*4);
  int*   bsums  = (int*)  alloc(64*4);
  int*   col    = (int*)  alloc((size_t)E*4);
  float* dis    = (float*)alloc((size_t)n*4);
  float* bufB   = (float*)alloc((size_t)n*64*4);
  float* bufC   = (float*)alloc((size_t)n*64*4);
  float* stats  = (float*)alloc(128*4);
  float* ac     = (float*)alloc(128*4);
  int*   gs     = (int*)  alloc((size_t)(G+1)*4);
  float* pooled = (float*)alloc((size_t)G*64*4);

  hipMemsetAsync(cnt, 0, (size_t)n*4, stream);
  k_hist<<<1024,256,0,stream>>>(dst, E, cnt);
  k_dis <<<512,256,0,stream>>>(cnt, dis, n);
  int nb1 = (n + 2047) / 2048;
  k_scan1<<<nb1,256,0,stream>>>(cnt, rowptr, bsums, n);
  k_scan2<<<1,64,0,stream>>>(bsums, nb1);
  k_scan3<<<512,256,0,stream>>>(rowptr, cursor, bsums, n, E);
  k_fill<<<1024,256,0,stream>>>(src, dst, E, cursor, col);
  k_gsinit<<<4,256,0,stream>>>(gs, G, n);
  k_gsbound<<<512,256,0,stream>>>(batch, n, gs);

  int nch = (n + 31) / 32;
  int gg  = (nch + 3) / 4;

  // layer 1
  k_gemm<128,false><<<gg,256,0,stream>>>(x, W1, dis, nullptr, bufB, n, nch);
  hipMemsetAsync(stats, 0, 512, stream);
  k_agg<<<1024,256,0,stream>>>(bufB, rowptr, col, dis, b1, bufC, stats, n);
  k_final<<<1,64,0,stream>>>(stats, g1, bt1, ac, n);
  // layer 2
  k_gemm<64,true><<<gg,256,0,stream>>>(bufC, W2, dis, ac, bufB, n, nch);
  hipMemsetAsync(stats, 0, 512, stream);
  k_agg<<<1024,256,0,stream>>>(bufB, rowptr, col, dis, b2, bufC, stats, n);
  k_final<<<1,64,0,stream>>>(stats, g2, bt2, ac, n);
  // layer 3
  k_gemm<64,true><<<gg,256,0,stream>>>(bufC, W3, dis, ac, bufB, n, nch);
  hipMemsetAsync(stats, 0, 512, stream);
  k_agg<<<1024,256,0,stream>>>(bufB, rowptr, col, dis, b3, bufC, stats, n);
  k_final<<<1,64,0,stream>>>(stats, g3, bt3, ac, n);
  // layer 4
  k_gemm<64,true><<<gg,256,0,stream>>>(bufC, W4, dis, ac, bufB, n, nch);
  hipMemsetAsync(stats, 0, 512, stream);
  k_agg<<<1024,256,0,stream>>>(bufB, rowptr, col, dis, b4, bufC, stats, n);
  k_final<<<1,64,0,stream>>>(stats, g4, bt4, ac, n);

  k_pool<<<G,256,0,stream>>>(bufC, ac, gs, pooled);
  k_logits<<<(G*64 + 255)/256,256,0,stream>>>(pooled, fcW, fcb, (float*)d_out, G);
}

// Round 2
// 705.020 us; speedup vs baseline: 1.3197x; 1.3197x over previous
//
#include <hip/hip_runtime.h>

#define EPSV 1e-5f
#define BSH 6   // 64 nodes per bucket

// ---------------- bucketed CSR build ----------------
__global__ __launch_bounds__(256) void k_bhist(const int* __restrict__ dst, int E, int nb,
                                               int* __restrict__ bhist){
  extern __shared__ int lh[];
  for (int t = threadIdx.x; t < nb; t += 256) lh[t] = 0;
  __syncthreads();
  for (int e = blockIdx.x*256+threadIdx.x; e < E; e += gridDim.x*256)
    atomicAdd(&lh[dst[e]>>BSH], 1);
  __syncthreads();
  for (int t = threadIdx.x; t < nb; t += 256){ int v = lh[t]; if (v) atomicAdd(&bhist[t], v); }
}

// single-block exclusive scan of bhist[nb] -> boff, bcur ; boff[nb]=E ; rowptr[n]=E
__global__ __launch_bounds__(256) void k_bscan(const int* __restrict__ bhist, int nb,
                                               int* __restrict__ boff, int* __restrict__ bcur,
                                               int* __restrict__ rowptr, int n, int E){
  __shared__ int sh[2][256];
  int tid = threadIdx.x;
  int per = (nb + 255) / 256;          // <=8 for nb<=2048
  int base = tid*per;
  int v[8]; int s = 0;
  for (int j=0;j<per;++j){ int i=base+j; v[j] = (i<nb)? bhist[i]:0; s += v[j]; }
  sh[0][tid] = s; __syncthreads();
  int pa = 0;
  for (int off=1; off<256; off<<=1){
    int add = (tid>=off)? sh[pa][tid-off] : 0;
    sh[pa^1][tid] = sh[pa][tid] + add;
    pa ^= 1; __syncthreads();
  }
  int run = sh[pa][tid] - s;
  for (int j=0;j<per;++j){ int i=base+j; if (i<nb){ boff[i]=run; bcur[i]=run; run += v[j]; } }
  if (tid==255) boff[nb] = E;
  if (tid==254) rowptr[n] = E;
}

// scatter packed (ldst<<25 | src) into bucket regions
__global__ __launch_bounds__(256) void k_bscatter(const int* __restrict__ src, const int* __restrict__ dst,
                                                  int E, int nb, int nchunk,
                                                  int* __restrict__ bcur, unsigned* __restrict__ ebuf){
  extern __shared__ int lh[];
  int s = blockIdx.x*nchunk, e = min(E, s+nchunk);
  for (int t = threadIdx.x; t < nb; t += 256) lh[t] = 0;
  __syncthreads();
  for (int i = s+threadIdx.x; i < e; i += 256) atomicAdd(&lh[dst[i]>>BSH], 1);
  __syncthreads();
  for (int t = threadIdx.x; t < nb; t += 256){
    int v = lh[t];
    lh[t] = v ? atomicAdd(&bcur[t], v) : 0;
  }
  __syncthreads();
  for (int i = s+threadIdx.x; i < e; i += 256){
    int d = dst[i];
    int pos = atomicAdd(&lh[d>>BSH], 1);
    ebuf[pos] = (unsigned)src[i] | ((unsigned)(d & 63) << 25);
  }
}

// one block per bucket: counting sort -> col ; emits rowptr + dis
__global__ __launch_bounds__(256) void k_bsort(const unsigned* __restrict__ ebuf, const int* __restrict__ boff,
                                               int n, int* __restrict__ rowptr, int* __restrict__ col,
                                               float* __restrict__ dis){
  __shared__ int cnt[64]; __shared__ int cur[64];
  int b = blockIdx.x;
  int s = boff[b], e = boff[b+1];
  if (threadIdx.x < 64) cnt[threadIdx.x] = 0;
  __syncthreads();
  for (int i = s+threadIdx.x; i < e; i += 256) atomicAdd(&cnt[ebuf[i]>>25], 1);
  __syncthreads();
  if (threadIdx.x < 64){
    int v = cnt[threadIdx.x];
    int inc = v;
    for (int off=1; off<64; off<<=1){ int u = __shfl_up(inc, off); if (threadIdx.x >= off) inc += u; }
    int ex = inc - v;
    cur[threadIdx.x] = s + ex;
    int node = b*64 + threadIdx.x;
    if (node < n){ rowptr[node] = s + ex; dis[node] = rsqrtf((float)(v+1)); }
  }
  __syncthreads();
  for (int i = s+threadIdx.x; i < e; i += 256){
    unsigned w = ebuf[i];
    int pos = atomicAdd(&cur[w>>25], 1);
    col[pos] = (int)(w & 0x1FFFFFFu);
  }
}

// ---------------- graph segment offsets (batch is sorted) ----------------
__global__ __launch_bounds__(256) void k_gsinit(int* __restrict__ gs, int G, int n){
  for (int t = blockIdx.x*256+threadIdx.x; t<=G; t+=gridDim.x*256) gs[t] = n;
}
__global__ __launch_bounds__(256) void k_gsbound(const int* __restrict__ batch, int n, int* __restrict__ gs){
  for (int i = blockIdx.x*256+threadIdx.x; i<n; i+=gridDim.x*256){
    int b = batch[i];
    int prev = (i==0)? -1 : batch[i-1];
    for (int g = prev+1; g<=b; ++g) gs[g] = i;
  }
}

// ---------------- GEMM: out[i][:] = dis[i] * (bnrelu?(X[i,:]) @ W) ----------------
template<int K, bool BN>
__global__ __launch_bounds__(256) void k_gemm(const float* __restrict__ X, const float* __restrict__ W,
    const float* __restrict__ dis, const float* __restrict__ stats,
    const float* __restrict__ g, const float* __restrict__ bt,
    float* __restrict__ out, int n, int nchunks)
{
  __shared__ float4 Wl[K*16];
  __shared__ float2 acS[64];
  for (int t = threadIdx.x; t < K*16; t += 256)
    Wl[t] = reinterpret_cast<const float4*>(W)[t];
  if (BN && threadIdx.x < 64){
    int j = threadIdx.x;
    float fn = (float)n;
    float mu = stats[j]/fn;
    float var = stats[64+j]/fn - mu*mu;
    float a = rsqrtf(var + EPSV) * g[j];
    acS[j] = make_float2(a, bt[j] - mu*a);
  }
  __syncthreads();
  int wave = threadIdx.x>>6, lane = threadIdx.x&63;
  int cg = lane&15, rg = lane>>4;
  for (int chunk = blockIdx.x*4+wave; chunk < nchunks; chunk += gridDim.x*4){
    int rowbase = chunk*32 + rg*8;
    float4 acc[8];
    #pragma unroll
    for (int r=0;r<8;++r) acc[r] = make_float4(0.f,0.f,0.f,0.f);
    for (int k=0;k<K;k+=4){
      float4 w0 = Wl[(k+0)*16+cg];
      float4 w1 = Wl[(k+1)*16+cg];
      float4 w2 = Wl[(k+2)*16+cg];
      float4 w3 = Wl[(k+3)*16+cg];
      float2 p0,p1,p2,p3;
      if (BN){ p0=acS[k]; p1=acS[k+1]; p2=acS[k+2]; p3=acS[k+3]; }
      #pragma unroll
      for (int r=0;r<8;++r){
        int row = rowbase+r;
        float4 xq = make_float4(0.f,0.f,0.f,0.f);
        if (row < n) xq = *reinterpret_cast<const float4*>(X + (size_t)row*K + k);
        if (BN){
          xq.x = fmaxf(fmaf(xq.x,p0.x,p0.y), 0.f);
          xq.y = fmaxf(fmaf(xq.y,p1.x,p1.y), 0.f);
          xq.z = fmaxf(fmaf(xq.z,p2.x,p2.y), 0.f);
          xq.w = fmaxf(fmaf(xq.w,p3.x,p3.y), 0.f);
        }
        acc[r].x = fmaf(xq.w,w3.x, fmaf(xq.z,w2.x, fmaf(xq.y,w1.x, fmaf(xq.x,w0.x, acc[r].x))));
        acc[r].y = fmaf(xq.w,w3.y, fmaf(xq.z,w2.y, fmaf(xq.y,w1.y, fmaf(xq.x,w0.y, acc[r].y))));
        acc[r].z = fmaf(xq.w,w3.z, fmaf(xq.z,w2.z, fmaf(xq.y,w1.z, fmaf(xq.x,w0.z, acc[r].z))));
        acc[r].w = fmaf(xq.w,w3.w, fmaf(xq.z,w2.w, fmaf(xq.y,w1.w, fmaf(xq.x,w0.w, acc[r].w))));
      }
    }
    #pragma unroll
    for (int r=0;r<8;++r){
      int row = rowbase+r;
      if (row < n){
        float d = dis[row];
        float4 o = make_float4(acc[r].x*d, acc[r].y*d, acc[r].z*d, acc[r].w*d);
        *reinterpret_cast<float4*>(out + (size_t)row*64 + cg*4) = o;
      }
    }
  }
}

// ---------------- aggregation + bias + BN-stat partials ----------------
__global__ __launch_bounds__(256) void k_agg(const float* __restrict__ H, const int* __restrict__ rp,
    const int* __restrict__ col, const float* __restrict__ dis, const float* __restrict__ bias,
    float* __restrict__ out, float* __restrict__ stats, int n)
{
  int wave = threadIdx.x>>6, lane = threadIdx.x&63;
  float bj = bias[lane];
  float bsum = 0.f, bsq = 0.f;
  int nw = gridDim.x*4;
  for (int i = blockIdx.x*4+wave; i<n; i+=nw){
    int s = rp[i], e = rp[i+1];
    float acc = H[(size_t)i*64+lane];
    int t = s;
    for (; t+8 <= e; t += 8){
      int c0 = col[t],   c1 = col[t+1], c2 = col[t+2], c3 = col[t+3];
      int c4 = col[t+4], c5 = col[t+5], c6 = col[t+6], c7 = col[t+7];
      float v0 = H[(size_t)c0*64+lane];
      float v1 = H[(size_t)c1*64+lane];
      float v2 = H[(size_t)c2*64+lane];
      float v3 = H[(size_t)c3*64+lane];
      float v4 = H[(size_t)c4*64+lane];
      float v5 = H[(size_t)c5*64+lane];
      float v6 = H[(size_t)c6*64+lane];
      float v7 = H[(size_t)c7*64+lane];
      acc += ((v0+v1)+(v2+v3)) + ((v4+v5)+(v6+v7));
    }
    for (; t+4 <= e; t += 4){
      int c0 = col[t], c1 = col[t+1], c2 = col[t+2], c3 = col[t+3];
      float v0 = H[(size_t)c0*64+lane];
      float v1 = H[(size_t)c1*64+lane];
      float v2 = H[(size_t)c2*64+lane];
      float v3 = H[(size_t)c3*64+lane];
      acc += (v0+v1)+(v2+v3);
    }
    for (; t<e; ++t) acc += H[(size_t)col[t]*64+lane];
    float v = fmaf(dis[i], acc, bj);
    out[(size_t)i*64+lane] = v;
    bsum += v; bsq = fmaf(v, v, bsq);
  }
  __shared__ float red[2][4][64];
  red[0][wave][lane] = bsum; red[1][wave][lane] = bsq;
  __syncthreads();
  if (wave==0){
    float s0 = (red[0][0][lane]+red[0][1][lane]) + (red[0][2][lane]+red[0][3][lane]);
    float q0 = (red[1][0][lane]+red[1][1][lane]) + (red[1][2][lane]+red[1][3][lane]);
    atomicAdd(&stats[lane], s0);
    atomicAdd(&stats[64+lane], q0);
  }
}

// ---------------- mean-pool with fused BN+ReLU ----------------
__global__ __launch_bounds__(256) void k_pool(const float* __restrict__ agg, const float* __restrict__ stats,
                                              const float* __restrict__ g, const float* __restrict__ bt,
                                              const int* __restrict__ gs, float* __restrict__ pooled, int n){
  __shared__ float2 acS[64];
  if (threadIdx.x < 64){
    int j = threadIdx.x;
    float fn = (float)n;
    float mu = stats[j]/fn;
    float var = stats[64+j]/fn - mu*mu;
    float a = rsqrtf(var + EPSV) * g[j];
    acS[j] = make_float2(a, bt[j] - mu*a);
  }
  __syncthreads();
  int gr = blockIdx.x;
  int s = gs[gr], e = gs[gr+1];
  int wave = threadIdx.x>>6, lane = threadIdx.x&63;
  float a = acS[lane].x, c = acS[lane].y;
  float acc = 0.f;
  for (int i = s+wave; i < e; i += 4)
    acc += fmaxf(fmaf(agg[(size_t)i*64+lane], a, c), 0.f);
  __shared__ float red[4][64];
  red[wave][lane] = acc; __syncthreads();
  if (wave==0){
    float t = (red[0][lane]+red[1][lane]) + (red[2][lane]+red[3][lane]);
    float cg = (float)(e - s);
    pooled[(size_t)gr*64+lane] = t / fmaxf(cg, 1.f);
  }
}

// ---------------- FC + log_softmax ----------------
__global__ __launch_bounds__(256) void k_logits(const float* __restrict__ pooled, const float* __restrict__ fcW,
                                                const float* __restrict__ fcb, float* __restrict__ out, int G){
  int gw = (blockIdx.x*256 + threadIdx.x) >> 6;
  int lane = threadIdx.x & 63;
  if (gw >= G) return;
  float l = -1e30f;
  if (lane < 10){
    l = fcb[lane];
    for (int k=0;k<64;++k) l = fmaf(pooled[(size_t)gw*64+k], fcW[k*10+lane], l);
  }
  float m = l;
  for (int off=32; off; off>>=1) m = fmaxf(m, __shfl_xor(m, off));
  float ex = (lane<10)? expf(l-m) : 0.f;
  float ssum = ex;
  for (int off=32; off; off>>=1) ssum += __shfl_xor(ssum, off);
  if (lane < 10) out[(size_t)gw*10+lane] = l - m - logf(ssum);
}

extern "C" void kernel_launch(void* const* d_in, const int* in_sizes, int n_in,
                              void* d_out, int out_size, void* d_ws, size_t ws_size,
                              hipStream_t stream){
  const float* x    = (const float*)d_in[0];
  const int*   ei   = (const int*)d_in[1];
  const int*   batch= (const int*)d_in[2];
  const float* W1 = (const float*)d_in[3];  const float* b1 = (const float*)d_in[4];
  const float* g1 = (const float*)d_in[5];  const float* bt1= (const float*)d_in[6];
  const float* W2 = (const float*)d_in[7];  const float* b2 = (const float*)d_in[8];
  const float* g2 = (const float*)d_in[9];  const float* bt2= (const float*)d_in[10];
  const float* W3 = (const float*)d_in[11]; const float* b3 = (const float*)d_in[12];
  const float* g3 = (const float*)d_in[13]; const float* bt3= (const float*)d_in[14];
  const float* W4 = (const float*)d_in[15]; const float* b4 = (const float*)d_in[16];
  const float* g4 = (const float*)d_in[17]; const float* bt4= (const float*)d_in[18];
  const float* fcW= (const float*)d_in[19]; const float* fcb= (const float*)d_in[20];

  int n = in_sizes[0] / 128;
  int E = in_sizes[1] / 2;
  int G = out_size / 10;
  const int* src = ei;
  const int* dst = ei + E;
  int nb = (n + 63) >> 6;

  // workspace carve (256B aligned)
  char* p = (char*)d_ws;
  auto alloc = [&](size_t bytes)->void*{ void* r = p; p += (bytes + 255) & ~(size_t)255; return r; };
  int*   bhist  = (int*)  alloc((size_t)nb*4);
  int*   boff   = (int*)  alloc((size_t)(nb+1)*4);
  int*   bcur   = (int*)  alloc((size_t)nb*4);
  int*   rowptr = (int*)  alloc((size_t)(n+1)*4);
  int*   col    = (int*)  alloc((size_t)E*4);
  float* dis    = (float*)alloc((size_t)n*4);
  float* bufB   = (float*)alloc((size_t)n*64*4);
  float* bufC   = (float*)alloc((size_t)n*64*4);
  float* stats  = (float*)alloc(4*128*4);
  int*   gs     = (int*)  alloc((size_t)(G+1)*4);
  float* pooled = (float*)alloc((size_t)G*64*4);
  unsigned* ebuf = (unsigned*)bufB;   // alias: dead before gemm1 writes bufB

  hipMemsetAsync(bhist, 0, (size_t)nb*4, stream);
  hipMemsetAsync(stats, 0, 4*128*4, stream);

  size_t ldsb = (size_t)nb*4;
  k_bhist<<<256,256,ldsb,stream>>>(dst, E, nb, bhist);
  k_bscan<<<1,256,0,stream>>>(bhist, nb, boff, bcur, rowptr, n, E);
  int nchunk = (E + 255) / 256;
  k_bscatter<<<256,256,ldsb,stream>>>(src, dst, E, nb, nchunk, bcur, ebuf);
  k_bsort<<<nb,256,0,stream>>>(ebuf, boff, n, rowptr, col, dis);
  k_gsinit<<<4,256,0,stream>>>(gs, G, n);
  k_gsbound<<<512,256,0,stream>>>(batch, n, gs);

  int nch = (n + 31) / 32;
  int gg  = (nch + 3) / 4;

  // layer 1
  k_gemm<128,false><<<gg,256,0,stream>>>(x, W1, dis, nullptr, nullptr, nullptr, bufB, n, nch);
  k_agg<<<2048,256,0,stream>>>(bufB, rowptr, col, dis, b1, bufC, stats+0, n);
  // layer 2
  k_gemm<64,true><<<gg,256,0,stream>>>(bufC, W2, dis, stats+0, g2, bt2, bufB, n, nch);
  k_agg<<<2048,256,0,stream>>>(bufB, rowptr, col, dis, b2, bufC, stats+128, n);
  // layer 3
  k_gemm<64,true><<<gg,256,0,stream>>>(bufC, W3, dis, stats+128, g3, bt3, bufB, n, nch);
  k_agg<<<2048,256,0,stream>>>(bufB, rowptr, col, dis, b3, bufC, stats+256, n);
  // layer 4
  k_gemm<64,true><<<gg,256,0,stream>>>(bufC, W4, dis, stats+256, g4, bt4, bufB, n, nch);
  k_agg<<<2048,256,0,stream>>>(bufB, rowptr, col, dis, b4, bufC, stats+384, n);

  k_pool<<<G,256,0,stream>>>(bufC, stats+384, g4, bt4, gs, pooled, n);
  k_logits<<<(G*64 + 255)/256,256,0,stream>>>(pooled, fcW, fcb, (float*)d_out, G);
}